// Round 9
// baseline (137.470 us; speedup 1.0000x reference)
//
#include <hip/hip_runtime.h>
#include <stdint.h>

#define NW   2048
#define OBS  512
#define HS   512
#define HS2  512
#define HM   256
#define CTX  128
#define ACT  18

#define K2LE 2.8853900817779268f   // 2*log2(e)

// ws layout (floats)
#define W1T_OFF   0          // [512 k][512 c]
#define WCT_OFF   262144     // [256 m][128 c]
#define W2T_OFF   294912     // [768 k][512 c]
#define WHHQ_OFF  688128     // [256 m][256 j] float4 (Wr,Wz,Wn,0)
#define FEAT_OFF  950272     // [2048][512]
#define GATES_OFF 1998848    // [2048][768]  (b_hh added)
#define HTERM_OFF 3571712    // [2048][128]  (K2LE-prescaled, bc added)
#define X_OFF     3833856    // [2048]
// total 3,835,904 floats = 15.3 MB

#if __has_builtin(__builtin_amdgcn_exp2f)
#define EXP2F(x) __builtin_amdgcn_exp2f(x)
#else
#define EXP2F(x) exp2f(x)
#endif
#if __has_builtin(__builtin_amdgcn_rcpf)
#define RCPF(x) __builtin_amdgcn_rcpf(x)
#else
#define RCPF(x) (1.0f/(x))
#endif

// ---------------- threefry2x32 (key = (0,42)), 20 rounds ----------------
#define TFR(x0, x1, R) { x0 += x1; x1 = (x1 << R) | (x1 >> (32 - R)); x1 ^= x0; }

__device__ __forceinline__ void threefry_0_42(uint32_t x0, uint32_t x1,
                                              uint32_t& o0, uint32_t& o1) {
    const uint32_t ks0 = 0u;
    const uint32_t ks1 = 42u;
    const uint32_t ks2 = 0x1BD11BDAu ^ ks0 ^ ks1;
    x0 += ks0; x1 += ks1;
    TFR(x0, x1, 13) TFR(x0, x1, 15) TFR(x0, x1, 26) TFR(x0, x1, 6)
    x0 += ks1; x1 += ks2 + 1u;
    TFR(x0, x1, 17) TFR(x0, x1, 29) TFR(x0, x1, 16) TFR(x0, x1, 24)
    x0 += ks2; x1 += ks0 + 2u;
    TFR(x0, x1, 13) TFR(x0, x1, 15) TFR(x0, x1, 26) TFR(x0, x1, 6)
    x0 += ks0; x1 += ks1 + 3u;
    TFR(x0, x1, 17) TFR(x0, x1, 29) TFR(x0, x1, 16) TFR(x0, x1, 24)
    x0 += ks1; x1 += ks2 + 4u;
    TFR(x0, x1, 13) TFR(x0, x1, 15) TFR(x0, x1, 26) TFR(x0, x1, 6)
    x0 += ks2; x1 += ks0 + 5u;
    o0 = x0; o1 = x1;
}

// jax_threefry_partitionable scheme (verified round 2): counter=(0,n), out0^out1
__device__ __forceinline__ float gumbel_ra(int row, int a) {
    uint32_t n = (uint32_t)(row * ACT + a);
    uint32_t o0, o1;
    threefry_0_42(0u, n, o0, o1);
    uint32_t bits = o0 ^ o1;
    uint32_t fb = (bits >> 9) | 0x3F800000u;
    float f = __uint_as_float(fb) - 1.0f;
    const float tiny = 1.17549435e-38f;
    float u = (f < tiny) ? tiny : f;
    return -logf(-logf(u));
}

__device__ __forceinline__ float fast_tanh(float x) {
    float e = __expf(2.0f * x);
    return 1.0f - 2.0f / (e + 1.0f);
}
__device__ __forceinline__ float fast_sig(float x) {
    return 1.0f / (1.0f + __expf(-x));
}

// ---- weight prep: transposes + GRU gate-pack into ws (proven in r5-r7) ----
__global__ __launch_bounds__(256) void transpose_weights(
    const float* __restrict__ W1, const float* __restrict__ Wc,
    const float* __restrict__ Whh, const float* __restrict__ W2,
    float* __restrict__ ws)
{
    __shared__ float t[3][32][33];
    const int tx = threadIdx.x & 31, ty = threadIdx.x >> 5;   // 32 x 8
    int b = blockIdx.x;
    if (b < 672) {
        const float* src; float* dst; int ld, off, R, it, jt;
        if (b < 256)      { src = W1;  dst = ws + W1T_OFF;  ld = 512; off = 0; it = b >> 4; jt = b & 15; R = 512; }
        else if (b < 288) { int bb = b - 256; src = Wc;  dst = ws + WCT_OFF;  ld = 257; off = 1; it = bb >> 3; jt = bb & 7;  R = 128; }
        else              { int bb = b - 288; src = W2;  dst = ws + W2T_OFF;  ld = 768; off = 0; it = bb / 24; jt = bb % 24; R = 512; }
        const int i0 = it * 32, j0 = jt * 32;
        #pragma unroll
        for (int q = 0; q < 4; ++q)
            t[0][ty + 8 * q][tx] = src[(i0 + ty + 8 * q) * ld + off + j0 + tx];
        __syncthreads();
        #pragma unroll
        for (int q = 0; q < 4; ++q)
            dst[(j0 + ty + 8 * q) * R + i0 + tx] = t[0][tx][ty + 8 * q];
    } else {
        int bb = b - 672;
        const int mt = bb >> 3, jt = bb & 7;
        const int m0 = mt * 32, j0 = jt * 32;
        #pragma unroll
        for (int g = 0; g < 3; ++g)
            #pragma unroll
            for (int q = 0; q < 4; ++q)
                t[g][ty + 8 * q][tx] = Whh[(g * HM + j0 + ty + 8 * q) * HM + m0 + tx];
        __syncthreads();
        float4* dst = (float4*)(ws + WHHQ_OFF);
        #pragma unroll
        for (int q = 0; q < 4; ++q) {
            int ml = ty + 8 * q, jl = tx;
            dst[(size_t)(m0 + ml) * HM + j0 + jl] =
                make_float4(t[0][jl][ml], t[1][jl][ml], t[2][jl][ml], 0.0f);
        }
    }
}

// ---- gemm8: 8 rows/block; wave owns full K; lanes own col-pairs/gate-cols ----
// grid: [0,256) feat; [256,512) gates; [512,768) hterm
__global__ __launch_bounds__(256) void gemm8(
    const float* __restrict__ obs, const float* __restrict__ hmem,
    const float* __restrict__ b1,  const float* __restrict__ bc,
    const float* __restrict__ bhh, float* __restrict__ ws)
{
    __shared__ float s_act[8 * 512];   // 16 KB max (feat); gates/hterm use 8*256
    const int tid = threadIdx.x;
    const int wv = tid >> 6, lane = tid & 63;
    const int bid = blockIdx.x;

    if (bid < 256) {
        // ---- feat = relu(obs @ W1T + b1): 8 rows x 512 cols, K=512 ----
        const int m0 = bid * 8;
        for (int i = tid; i < 1024; i += 256) {
            int r = i >> 7, kq = i & 127;
            *(float4*)&s_act[r * 512 + kq * 4] =
                *(const float4*)&obs[(size_t)(m0 + r) * 512 + kq * 4];
        }
        __syncthreads();
        const float2* __restrict__ Wt = (const float2*)(ws + W1T_OFF);  // [512][256 f2]
        const int c2 = wv * 64 + lane;
        float2 acc[8];
        #pragma unroll
        for (int r = 0; r < 8; ++r) acc[r] = make_float2(0.f, 0.f);
        #pragma unroll 2
        for (int k = 0; k < 512; k += 4) {
            float2 w0 = Wt[(k + 0) * 256 + c2];
            float2 w1 = Wt[(k + 1) * 256 + c2];
            float2 w2 = Wt[(k + 2) * 256 + c2];
            float2 w3 = Wt[(k + 3) * 256 + c2];
            #pragma unroll
            for (int r = 0; r < 8; ++r) {
                float4 o = *(const float4*)&s_act[r * 512 + k];  // uniform broadcast
                acc[r].x = fmaf(o.x, w0.x, acc[r].x); acc[r].y = fmaf(o.x, w0.y, acc[r].y);
                acc[r].x = fmaf(o.y, w1.x, acc[r].x); acc[r].y = fmaf(o.y, w1.y, acc[r].y);
                acc[r].x = fmaf(o.z, w2.x, acc[r].x); acc[r].y = fmaf(o.z, w2.y, acc[r].y);
                acc[r].x = fmaf(o.w, w3.x, acc[r].x); acc[r].y = fmaf(o.w, w3.y, acc[r].y);
            }
        }
        float2 bb = ((const float2*)b1)[c2];
        float* F = ws + FEAT_OFF;
        #pragma unroll
        for (int r = 0; r < 8; ++r) {
            float2 v;
            v.x = fmaxf(acc[r].x + bb.x, 0.f);
            v.y = fmaxf(acc[r].y + bb.y, 0.f);
            *(float2*)&F[(size_t)(m0 + r) * 512 + c2 * 2] = v;
        }
    } else if (bid < 512) {
        // ---- gates = h @ WhhT + b_hh: 8 rows x 256 j x 3 gates, K=256 ----
        const int m0 = (bid - 256) * 8;
        for (int i = tid; i < 512; i += 256) {
            int r = i >> 6, kq = i & 63;
            *(float4*)&s_act[r * 256 + kq * 4] =
                *(const float4*)&hmem[(size_t)(m0 + r) * 256 + kq * 4];
        }
        __syncthreads();
        const float4* __restrict__ Q = (const float4*)(ws + WHHQ_OFF);  // [256][256]
        const int j = wv * 64 + lane;
        float ar[8] = {0,0,0,0,0,0,0,0}, az[8] = {0,0,0,0,0,0,0,0}, an[8] = {0,0,0,0,0,0,0,0};
        #pragma unroll 2
        for (int k = 0; k < 256; k += 4) {
            float4 q0 = Q[(k + 0) * 256 + j];
            float4 q1 = Q[(k + 1) * 256 + j];
            float4 q2 = Q[(k + 2) * 256 + j];
            float4 q3 = Q[(k + 3) * 256 + j];
            #pragma unroll
            for (int r = 0; r < 8; ++r) {
                float4 h = *(const float4*)&s_act[r * 256 + k];  // uniform broadcast
                ar[r] = fmaf(h.x, q0.x, ar[r]); az[r] = fmaf(h.x, q0.y, az[r]); an[r] = fmaf(h.x, q0.z, an[r]);
                ar[r] = fmaf(h.y, q1.x, ar[r]); az[r] = fmaf(h.y, q1.y, az[r]); an[r] = fmaf(h.y, q1.z, an[r]);
                ar[r] = fmaf(h.z, q2.x, ar[r]); az[r] = fmaf(h.z, q2.y, az[r]); an[r] = fmaf(h.z, q2.z, an[r]);
                ar[r] = fmaf(h.w, q3.x, ar[r]); az[r] = fmaf(h.w, q3.y, az[r]); an[r] = fmaf(h.w, q3.z, an[r]);
            }
        }
        float br = bhh[j], bz = bhh[HM + j], bn = bhh[2 * HM + j];
        float* G = ws + GATES_OFF;
        #pragma unroll
        for (int r = 0; r < 8; ++r) {
            size_t base = (size_t)(m0 + r) * 768 + j;
            G[base]       = ar[r] + br;
            G[base + 256] = az[r] + bz;
            G[base + 512] = an[r] + bn;
        }
    } else {
        // ---- hterm = K2LE*(h @ WcT + bc): 8 rows x 128 cols, K=256 ----
        const int m0 = (bid - 512) * 8;
        for (int i = tid; i < 512; i += 256) {
            int r = i >> 6, kq = i & 63;
            *(float4*)&s_act[r * 256 + kq * 4] =
                *(const float4*)&hmem[(size_t)(m0 + r) * 256 + kq * 4];
        }
        __syncthreads();
        const float2* __restrict__ Wt = (const float2*)(ws + WCT_OFF);  // [256][64 f2]
        const int r0 = wv * 2;
        float2 a0 = make_float2(0.f, 0.f), a1 = make_float2(0.f, 0.f);
        #pragma unroll 2
        for (int k = 0; k < 256; k += 4) {
            float2 w0 = Wt[(k + 0) * 64 + lane];
            float2 w1 = Wt[(k + 1) * 64 + lane];
            float2 w2 = Wt[(k + 2) * 64 + lane];
            float2 w3 = Wt[(k + 3) * 64 + lane];
            float4 o0 = *(const float4*)&s_act[r0 * 256 + k];
            float4 o1 = *(const float4*)&s_act[(r0 + 1) * 256 + k];
            a0.x = fmaf(o0.x, w0.x, a0.x); a0.y = fmaf(o0.x, w0.y, a0.y);
            a0.x = fmaf(o0.y, w1.x, a0.x); a0.y = fmaf(o0.y, w1.y, a0.y);
            a0.x = fmaf(o0.z, w2.x, a0.x); a0.y = fmaf(o0.z, w2.y, a0.y);
            a0.x = fmaf(o0.w, w3.x, a0.x); a0.y = fmaf(o0.w, w3.y, a0.y);
            a1.x = fmaf(o1.x, w0.x, a1.x); a1.y = fmaf(o1.x, w0.y, a1.y);
            a1.x = fmaf(o1.y, w1.x, a1.x); a1.y = fmaf(o1.y, w1.y, a1.y);
            a1.x = fmaf(o1.z, w2.x, a1.x); a1.y = fmaf(o1.z, w2.y, a1.y);
            a1.x = fmaf(o1.w, w3.x, a1.x); a1.y = fmaf(o1.w, w3.y, a1.y);
        }
        float2 bb = ((const float2*)bc)[lane];
        float* H = ws + HTERM_OFF;
        float2 v0, v1;
        v0.x = K2LE * (a0.x + bb.x); v0.y = K2LE * (a0.y + bb.y);
        v1.x = K2LE * (a1.x + bb.x); v1.y = K2LE * (a1.y + bb.y);
        *(float2*)&H[(size_t)(m0 + r0) * 128 + lane * 2]     = v0;
        *(float2*)&H[(size_t)(m0 + r0 + 1) * 128 + lane * 2] = v1;
    }
}

// ---- attention: tanh ctx + softmax + dset -> x; 8 rows/block ----
__global__ __launch_bounds__(512) void attn_kernel(
    const float* __restrict__ obs, const float* __restrict__ Wc,
    const float* __restrict__ Wa,  const float* __restrict__ ba,
    float* __restrict__ ws)
{
    __shared__ float s_obs[8][512];    // 16 KB
    __shared__ float s_ht[8][128];     // 4 KB (K2LE-prescaled)
    __shared__ float s_alog[8][512];   // 16 KB
    __shared__ float s_wc0[128], s_wa2[128];

    const int tid = threadIdx.x;
    const int row0 = blockIdx.x * 8;
    const float* hterm = ws + HTERM_OFF;
    float* X = ws + X_OFF;

    for (int i = tid; i < 1024; i += 512) {
        int r = i >> 7, kq = i & 127;
        *(float4*)&s_obs[r][kq * 4] =
            *(const float4*)&obs[(size_t)(row0 + r) * 512 + kq * 4];
    }
    if (tid < 256) {
        int r = tid >> 5, kq = tid & 31;
        *(float4*)&s_ht[r][kq * 4] =
            *(const float4*)&hterm[(size_t)(row0 + r) * 128 + kq * 4];
    }
    if (tid < 128) {
        s_wc0[tid] = K2LE * Wc[tid * (HM + 1)];
        s_wa2[tid] = 2.0f * Wa[tid];
    }
    __syncthreads();

    {
        const float ba0 = ba[0];
        const int o = tid;
        float ob[8], acA[8];
        #pragma unroll
        for (int r = 0; r < 8; ++r) { ob[r] = s_obs[r][o]; acA[r] = 0.f; }
        float swa = 0.f;
        for (int c = 0; c < 128; c += 4) {
            float4 v = *(const float4*)&s_wa2[c];
            swa += v.x + v.y + v.z + v.w;
        }
        swa *= 0.5f;
        for (int c4 = 0; c4 < 32; ++c4) {
            float4 wc = *(const float4*)&s_wc0[c4 * 4];
            float4 wa = *(const float4*)&s_wa2[c4 * 4];
            #pragma unroll
            for (int r = 0; r < 8; ++r) {
                float4 ht = *(const float4*)&s_ht[r][c4 * 4];
                float t0 = fmaf(ob[r], wc.x, ht.x);
                acA[r] = fmaf(wa.x, RCPF(EXP2F(t0) + 1.f), acA[r]);
                float t1 = fmaf(ob[r], wc.y, ht.y);
                acA[r] = fmaf(wa.y, RCPF(EXP2F(t1) + 1.f), acA[r]);
                float t2 = fmaf(ob[r], wc.z, ht.z);
                acA[r] = fmaf(wa.z, RCPF(EXP2F(t2) + 1.f), acA[r]);
                float t3 = fmaf(ob[r], wc.w, ht.w);
                acA[r] = fmaf(wa.w, RCPF(EXP2F(t3) + 1.f), acA[r]);
            }
        }
        #pragma unroll
        for (int r = 0; r < 8; ++r) s_alog[r][o] = ba0 + swa - acA[r];
    }
    __syncthreads();

    {
        const int wv = tid >> 6, lane = tid & 63;
        const int r = wv;
        float m = -1e30f;
        for (int o = lane; o < 512; o += 64) m = fmaxf(m, s_alog[r][o]);
        #pragma unroll
        for (int d = 32; d >= 1; d >>= 1) m = fmaxf(m, __shfl_xor(m, d));
        float se = 0.f, sw = 0.f;
        for (int o = lane; o < 512; o += 64) {
            float e = __expf(s_alog[r][o] - m);
            se += e; sw += e * s_obs[r][o];
        }
        #pragma unroll
        for (int d = 32; d >= 1; d >>= 1) { se += __shfl_xor(se, d); sw += __shfl_xor(sw, d); }
        if (lane == 0) X[row0 + r] = sw / se;
    }
}

// ---- fused: GRU-finish + out2 GEMM + heads + sampling; 8 rows/block ----
__global__ __launch_bounds__(256) void out2_heads(
    const float* __restrict__ hmem,  const float* __restrict__ W_ih,
    const float* __restrict__ b_ih,  const float* __restrict__ b2,
    const float* __restrict__ Wact,  const float* __restrict__ bact,
    const float* __restrict__ Wcrit, const float* __restrict__ bcrit,
    const float* __restrict__ ws,    float* __restrict__ out)
{
    __shared__ float s_act[8 * 768];   // 24 KB; aliased as s_out[8][512] after GEMM
    const int tid = threadIdx.x;
    const int wv = tid >> 6, lane = tid & 63;
    const int m0 = blockIdx.x * 8;
    const float* F = ws + FEAT_OFF;
    const float* G = ws + GATES_OFF;
    const float* X = ws + X_OFF;

    // stage feat rows into [r][0..512)
    for (int i = tid; i < 1024; i += 256) {
        int r = i >> 7, kq = i & 127;
        *(float4*)&s_act[r * 768 + kq * 4] =
            *(const float4*)&F[(size_t)(m0 + r) * 512 + kq * 4];
    }
    // GRU finish -> [r][512..768)
    for (int i = tid; i < 2048; i += 256) {
        int r = i >> 8, j = i & 255;
        int grow = m0 + r;
        float g0 = G[(size_t)grow * 768 + j];
        float g1 = G[(size_t)grow * 768 + 256 + j];
        float g2 = G[(size_t)grow * 768 + 512 + j];
        float hp = hmem[(size_t)grow * 256 + j];
        float x  = X[grow];
        float rg = fast_sig(fmaf(x, W_ih[j], b_ih[j]) + g0);
        float zg = fast_sig(fmaf(x, W_ih[256 + j], b_ih[256 + j]) + g1);
        float ng = fast_tanh(fmaf(x, W_ih[512 + j], b_ih[512 + j]) + rg * g2);
        s_act[r * 768 + 512 + j] = (1.0f - zg) * ng + zg * hp;
    }
    __syncthreads();

    // out2 GEMM: wave owns full K=768, lane owns col-pair c2
    const float2* __restrict__ Wt = (const float2*)(ws + W2T_OFF);  // [768][256 f2]
    const int c2 = wv * 64 + lane;
    float2 acc[8];
    #pragma unroll
    for (int r = 0; r < 8; ++r) acc[r] = make_float2(0.f, 0.f);
    #pragma unroll 2
    for (int k = 0; k < 768; k += 4) {
        float2 w0 = Wt[(k + 0) * 256 + c2];
        float2 w1 = Wt[(k + 1) * 256 + c2];
        float2 w2 = Wt[(k + 2) * 256 + c2];
        float2 w3 = Wt[(k + 3) * 256 + c2];
        #pragma unroll
        for (int r = 0; r < 8; ++r) {
            float4 o = *(const float4*)&s_act[r * 768 + k];  // uniform broadcast
            acc[r].x = fmaf(o.x, w0.x, acc[r].x); acc[r].y = fmaf(o.x, w0.y, acc[r].y);
            acc[r].x = fmaf(o.y, w1.x, acc[r].x); acc[r].y = fmaf(o.y, w1.y, acc[r].y);
            acc[r].x = fmaf(o.z, w2.x, acc[r].x); acc[r].y = fmaf(o.z, w2.y, acc[r].y);
            acc[r].x = fmaf(o.w, w3.x, acc[r].x); acc[r].y = fmaf(o.w, w3.y, acc[r].y);
        }
    }
    float2 bb = ((const float2*)b2)[c2];
    __syncthreads();                    // all s_act reads done; alias as s_out
    float (*s_out)[512] = (float (*)[512])s_act;
    #pragma unroll
    for (int r = 0; r < 8; ++r) {
        float2 v;
        v.x = fmaxf(acc[r].x + bb.x, 0.f);
        v.y = fmaxf(acc[r].y + bb.y, 0.f);
        *(float2*)&s_out[r][c2 * 2] = v;
    }
    __syncthreads();

    // heads: 4 waves, each handles rows wv and wv+4
    for (int rr = wv; rr < 8; rr += 4) {
        const int grow = m0 + rr;
        float4 x0 = *(const float4*)&s_out[rr][lane * 8];
        float4 x1 = *(const float4*)&s_out[rr][lane * 8 + 4];
        float la[ACT];
        #pragma unroll
        for (int a = 0; a < ACT; ++a) {
            const float4* wa4 = (const float4*)&Wact[a * HS2 + lane * 8];
            float4 w0 = wa4[0], w1 = wa4[1];
            float p = x0.x * w0.x + x0.y * w0.y + x0.z * w0.z + x0.w * w0.w
                    + x1.x * w1.x + x1.y * w1.y + x1.z * w1.z + x1.w * w1.w;
            #pragma unroll
            for (int d = 32; d >= 1; d >>= 1) p += __shfl_xor(p, d);
            la[a] = p + bact[a];
        }
        const float4* wc4 = (const float4*)&Wcrit[lane * 8];
        float4 w0 = wc4[0], w1 = wc4[1];
        float pv = x0.x * w0.x + x0.y * w0.y + x0.z * w0.z + x0.w * w0.w
                 + x1.x * w1.x + x1.y * w1.y + x1.z * w1.z + x1.w * w1.w;
        #pragma unroll
        for (int d = 32; d >= 1; d >>= 1) pv += __shfl_xor(pv, d);

        float g = (lane < ACT) ? gumbel_ra(grow, lane) : 0.0f;
        float best = -1e30f; int amax = 0;
        float mx = -1e30f;
        #pragma unroll
        for (int a = 0; a < ACT; ++a) {
            float g_ = __shfl(g, a);
            float y = la[a] + g_;
            if (y > best) { best = y; amax = a; }   // first-max tie-break
            mx = fmaxf(mx, la[a]);
        }
        float se = 0.f;
        #pragma unroll
        for (int a = 0; a < ACT; ++a) se += __expf(la[a] - mx);
        float lse = mx + logf(se);
        float lp = la[amax] - lse;
        if (lane == 0) {
            out[grow]          = (float)amax;
            out[NW + grow]     = pv + bcrit[0];
            out[2 * NW + grow] = lp;
        }
    }
}

extern "C" void kernel_launch(void* const* d_in, const int* in_sizes, int n_in,
                              void* d_out, int out_size, void* d_ws, size_t ws_size,
                              hipStream_t stream) {
    const float* obs   = (const float*)d_in[0];
    const float* hmem  = (const float*)d_in[1];
    const float* W1    = (const float*)d_in[2];
    const float* b1    = (const float*)d_in[3];
    const float* Wc    = (const float*)d_in[4];
    const float* bc    = (const float*)d_in[5];
    const float* Wa    = (const float*)d_in[6];
    const float* ba    = (const float*)d_in[7];
    const float* W_ih  = (const float*)d_in[8];
    const float* b_ih  = (const float*)d_in[9];
    const float* W_hh  = (const float*)d_in[10];
    const float* b_hh  = (const float*)d_in[11];
    const float* W2    = (const float*)d_in[12];
    const float* b2    = (const float*)d_in[13];
    const float* Wact  = (const float*)d_in[14];
    const float* bact  = (const float*)d_in[15];
    const float* Wcrit = (const float*)d_in[16];
    const float* bcrit = (const float*)d_in[17];
    float* ws = (float*)d_ws;

    transpose_weights<<<736, 256, 0, stream>>>(W1, Wc, W_hh, W2, ws);
    gemm8<<<768, 256, 0, stream>>>(obs, hmem, b1, bc, b_hh, ws);
    attn_kernel<<<256, 512, 0, stream>>>(obs, Wc, Wa, ba, ws);
    out2_heads<<<256, 256, 0, stream>>>(hmem, W_ih, b_ih, b2,
                                        Wact, bact, Wcrit, bcrit, ws, (float*)d_out);
}

// Round 10
// 125.775 us; speedup vs baseline: 1.0930x; 1.0930x over previous
//
#include <hip/hip_runtime.h>
#include <stdint.h>

#define NW   2048
#define OBS  512
#define HS   512
#define HS2  512
#define HM   256
#define CTX  128
#define ACT  18

#define K2LE 2.8853900817779268f   // 2*log2(e)

// ws layout (floats)
#define W1T_OFF   0          // [512 k][512 c]
#define WCT_OFF   262144     // [256 m][128 c]
#define W2T_OFF   294912     // [768 k][512 c]
#define WHHQ_OFF  688128     // [256 m][256 j] float4 (Wr,Wz,Wn,0)
#define FEAT_OFF  950272     // [2048][512]
#define GATES_OFF 1998848    // [2048][768]  (b_hh added)
#define HTERM_OFF 3571712    // [2048][128]  (K2LE-prescaled, bc added)
#define X_OFF     3833856    // [2048]

#if __has_builtin(__builtin_amdgcn_exp2f)
#define EXP2F(x) __builtin_amdgcn_exp2f(x)
#else
#define EXP2F(x) exp2f(x)
#endif
#if __has_builtin(__builtin_amdgcn_rcpf)
#define RCPF(x) __builtin_amdgcn_rcpf(x)
#else
#define RCPF(x) (1.0f/(x))
#endif

// ---------------- threefry2x32 (key = (0,42)), 20 rounds ----------------
#define TFR(x0, x1, R) { x0 += x1; x1 = (x1 << R) | (x1 >> (32 - R)); x1 ^= x0; }

__device__ __forceinline__ void threefry_0_42(uint32_t x0, uint32_t x1,
                                              uint32_t& o0, uint32_t& o1) {
    const uint32_t ks0 = 0u;
    const uint32_t ks1 = 42u;
    const uint32_t ks2 = 0x1BD11BDAu ^ ks0 ^ ks1;
    x0 += ks0; x1 += ks1;
    TFR(x0, x1, 13) TFR(x0, x1, 15) TFR(x0, x1, 26) TFR(x0, x1, 6)
    x0 += ks1; x1 += ks2 + 1u;
    TFR(x0, x1, 17) TFR(x0, x1, 29) TFR(x0, x1, 16) TFR(x0, x1, 24)
    x0 += ks2; x1 += ks0 + 2u;
    TFR(x0, x1, 13) TFR(x0, x1, 15) TFR(x0, x1, 26) TFR(x0, x1, 6)
    x0 += ks0; x1 += ks1 + 3u;
    TFR(x0, x1, 17) TFR(x0, x1, 29) TFR(x0, x1, 16) TFR(x0, x1, 24)
    x0 += ks1; x1 += ks2 + 4u;
    TFR(x0, x1, 13) TFR(x0, x1, 15) TFR(x0, x1, 26) TFR(x0, x1, 6)
    x0 += ks2; x1 += ks0 + 5u;
    o0 = x0; o1 = x1;
}

// jax_threefry_partitionable scheme (verified round 2): counter=(0,n), out0^out1
__device__ __forceinline__ float gumbel_ra(int row, int a) {
    uint32_t n = (uint32_t)(row * ACT + a);
    uint32_t o0, o1;
    threefry_0_42(0u, n, o0, o1);
    uint32_t bits = o0 ^ o1;
    uint32_t fb = (bits >> 9) | 0x3F800000u;
    float f = __uint_as_float(fb) - 1.0f;
    const float tiny = 1.17549435e-38f;
    float u = (f < tiny) ? tiny : f;
    return -logf(-logf(u));
}

__device__ __forceinline__ float fast_tanh(float x) {
    float e = __expf(2.0f * x);
    return 1.0f - 2.0f / (e + 1.0f);
}
__device__ __forceinline__ float fast_sig(float x) {
    return 1.0f / (1.0f + __expf(-x));
}

// ---- weight prep: transposes + GRU gate-pack into ws ----
__global__ __launch_bounds__(256) void transpose_weights(
    const float* __restrict__ W1, const float* __restrict__ Wc,
    const float* __restrict__ Whh, const float* __restrict__ W2,
    float* __restrict__ ws)
{
    __shared__ float t[3][32][33];
    const int tx = threadIdx.x & 31, ty = threadIdx.x >> 5;   // 32 x 8
    int b = blockIdx.x;
    if (b < 672) {
        const float* src; float* dst; int ld, off, R, it, jt;
        if (b < 256)      { src = W1;  dst = ws + W1T_OFF;  ld = 512; off = 0; it = b >> 4; jt = b & 15; R = 512; }
        else if (b < 288) { int bb = b - 256; src = Wc;  dst = ws + WCT_OFF;  ld = 257; off = 1; it = bb >> 3; jt = bb & 7;  R = 128; }
        else              { int bb = b - 288; src = W2;  dst = ws + W2T_OFF;  ld = 768; off = 0; it = bb / 24; jt = bb % 24; R = 512; }
        const int i0 = it * 32, j0 = jt * 32;
        #pragma unroll
        for (int q = 0; q < 4; ++q)
            t[0][ty + 8 * q][tx] = src[(i0 + ty + 8 * q) * ld + off + j0 + tx];
        __syncthreads();
        #pragma unroll
        for (int q = 0; q < 4; ++q)
            dst[(j0 + ty + 8 * q) * R + i0 + tx] = t[0][tx][ty + 8 * q];
    } else {
        int bb = b - 672;
        const int mt = bb >> 3, jt = bb & 7;
        const int m0 = mt * 32, j0 = jt * 32;
        #pragma unroll
        for (int g = 0; g < 3; ++g)
            #pragma unroll
            for (int q = 0; q < 4; ++q)
                t[g][ty + 8 * q][tx] = Whh[(g * HM + j0 + ty + 8 * q) * HM + m0 + tx];
        __syncthreads();
        float4* dst = (float4*)(ws + WHHQ_OFF);
        #pragma unroll
        for (int q = 0; q < 4; ++q) {
            int ml = ty + 8 * q, jl = tx;
            dst[(size_t)(m0 + ml) * HM + j0 + jl] =
                make_float4(t[0][jl][ml], t[1][jl][ml], t[2][jl][ml], 0.0f);
        }
    }
}

// ---- gemm8: 8 rows/block; wave owns full K; conflict-free broadcasts ----
// grid: [0,256) feat; [256,512) gates; [512,768) hterm
__global__ __launch_bounds__(256) void gemm8(
    const float* __restrict__ obs, const float* __restrict__ hmem,
    const float* __restrict__ b1,  const float* __restrict__ bc,
    const float* __restrict__ bhh, float* __restrict__ ws)
{
    __shared__ float s_act[8 * 512];
    const int tid = threadIdx.x;
    const int wv = tid >> 6, lane = tid & 63;
    const int bid = blockIdx.x;

    if (bid < 256) {
        // ---- feat = relu(obs @ W1T + b1): 8 rows x 512 cols, K=512 ----
        const int m0 = bid * 8;
        for (int i = tid; i < 1024; i += 256) {
            int r = i >> 7, kq = i & 127;
            *(float4*)&s_act[r * 512 + kq * 4] =
                *(const float4*)&obs[(size_t)(m0 + r) * 512 + kq * 4];
        }
        __syncthreads();
        const float2* __restrict__ Wt = (const float2*)(ws + W1T_OFF);  // [512][256 f2]
        const int c2 = wv * 64 + lane;
        float2 acc[8];
        #pragma unroll
        for (int r = 0; r < 8; ++r) acc[r] = make_float2(0.f, 0.f);
        #pragma unroll 4
        for (int k = 0; k < 512; k += 4) {
            float2 w0 = Wt[(k + 0) * 256 + c2];
            float2 w1 = Wt[(k + 1) * 256 + c2];
            float2 w2 = Wt[(k + 2) * 256 + c2];
            float2 w3 = Wt[(k + 3) * 256 + c2];
            #pragma unroll
            for (int r = 0; r < 8; ++r) {
                float4 o = *(const float4*)&s_act[r * 512 + k];  // uniform broadcast
                acc[r].x = fmaf(o.x, w0.x, acc[r].x); acc[r].y = fmaf(o.x, w0.y, acc[r].y);
                acc[r].x = fmaf(o.y, w1.x, acc[r].x); acc[r].y = fmaf(o.y, w1.y, acc[r].y);
                acc[r].x = fmaf(o.z, w2.x, acc[r].x); acc[r].y = fmaf(o.z, w2.y, acc[r].y);
                acc[r].x = fmaf(o.w, w3.x, acc[r].x); acc[r].y = fmaf(o.w, w3.y, acc[r].y);
            }
        }
        float2 bb = ((const float2*)b1)[c2];
        float* F = ws + FEAT_OFF;
        #pragma unroll
        for (int r = 0; r < 8; ++r) {
            float2 v;
            v.x = fmaxf(acc[r].x + bb.x, 0.f);
            v.y = fmaxf(acc[r].y + bb.y, 0.f);
            *(float2*)&F[(size_t)(m0 + r) * 512 + c2 * 2] = v;
        }
    } else if (bid < 512) {
        // ---- gates = h @ WhhT + b_hh: 8 rows x 256 j x 3 gates, K=256 ----
        const int m0 = (bid - 256) * 8;
        for (int i = tid; i < 512; i += 256) {
            int r = i >> 6, kq = i & 63;
            *(float4*)&s_act[r * 256 + kq * 4] =
                *(const float4*)&hmem[(size_t)(m0 + r) * 256 + kq * 4];
        }
        __syncthreads();
        const float4* __restrict__ Q = (const float4*)(ws + WHHQ_OFF);  // [256][256]
        const int j = wv * 64 + lane;
        float ar[8] = {0,0,0,0,0,0,0,0}, az[8] = {0,0,0,0,0,0,0,0}, an[8] = {0,0,0,0,0,0,0,0};
        #pragma unroll 4
        for (int k = 0; k < 256; k += 4) {
            float4 q0 = Q[(k + 0) * 256 + j];
            float4 q1 = Q[(k + 1) * 256 + j];
            float4 q2 = Q[(k + 2) * 256 + j];
            float4 q3 = Q[(k + 3) * 256 + j];
            #pragma unroll
            for (int r = 0; r < 8; ++r) {
                float4 h = *(const float4*)&s_act[r * 256 + k];  // uniform broadcast
                ar[r] = fmaf(h.x, q0.x, ar[r]); az[r] = fmaf(h.x, q0.y, az[r]); an[r] = fmaf(h.x, q0.z, an[r]);
                ar[r] = fmaf(h.y, q1.x, ar[r]); az[r] = fmaf(h.y, q1.y, az[r]); an[r] = fmaf(h.y, q1.z, an[r]);
                ar[r] = fmaf(h.z, q2.x, ar[r]); az[r] = fmaf(h.z, q2.y, az[r]); an[r] = fmaf(h.z, q2.z, an[r]);
                ar[r] = fmaf(h.w, q3.x, ar[r]); az[r] = fmaf(h.w, q3.y, az[r]); an[r] = fmaf(h.w, q3.z, an[r]);
            }
        }
        float br = bhh[j], bz = bhh[HM + j], bn = bhh[2 * HM + j];
        float* G = ws + GATES_OFF;
        #pragma unroll
        for (int r = 0; r < 8; ++r) {
            size_t base = (size_t)(m0 + r) * 768 + j;
            G[base]       = ar[r] + br;
            G[base + 256] = az[r] + bz;
            G[base + 512] = an[r] + bn;
        }
    } else {
        // ---- hterm = K2LE*(h @ WcT + bc): 8 rows x 128 cols, K=256 ----
        const int m0 = (bid - 512) * 8;
        for (int i = tid; i < 512; i += 256) {
            int r = i >> 6, kq = i & 63;
            *(float4*)&s_act[r * 256 + kq * 4] =
                *(const float4*)&hmem[(size_t)(m0 + r) * 256 + kq * 4];
        }
        __syncthreads();
        const float2* __restrict__ Wt = (const float2*)(ws + WCT_OFF);  // [256][64 f2]
        const int r0 = wv * 2;
        float2 a0 = make_float2(0.f, 0.f), a1 = make_float2(0.f, 0.f);
        #pragma unroll 4
        for (int k = 0; k < 256; k += 4) {
            float2 w0 = Wt[(k + 0) * 64 + lane];
            float2 w1 = Wt[(k + 1) * 64 + lane];
            float2 w2 = Wt[(k + 2) * 64 + lane];
            float2 w3 = Wt[(k + 3) * 64 + lane];
            float4 o0 = *(const float4*)&s_act[r0 * 256 + k];
            float4 o1 = *(const float4*)&s_act[(r0 + 1) * 256 + k];
            a0.x = fmaf(o0.x, w0.x, a0.x); a0.y = fmaf(o0.x, w0.y, a0.y);
            a0.x = fmaf(o0.y, w1.x, a0.x); a0.y = fmaf(o0.y, w1.y, a0.y);
            a0.x = fmaf(o0.z, w2.x, a0.x); a0.y = fmaf(o0.z, w2.y, a0.y);
            a0.x = fmaf(o0.w, w3.x, a0.x); a0.y = fmaf(o0.w, w3.y, a0.y);
            a1.x = fmaf(o1.x, w0.x, a1.x); a1.y = fmaf(o1.x, w0.y, a1.y);
            a1.x = fmaf(o1.y, w1.x, a1.x); a1.y = fmaf(o1.y, w1.y, a1.y);
            a1.x = fmaf(o1.z, w2.x, a1.x); a1.y = fmaf(o1.z, w2.y, a1.y);
            a1.x = fmaf(o1.w, w3.x, a1.x); a1.y = fmaf(o1.w, w3.y, a1.y);
        }
        float2 bb = ((const float2*)bc)[lane];
        float* H = ws + HTERM_OFF;
        float2 v0, v1;
        v0.x = K2LE * (a0.x + bb.x); v0.y = K2LE * (a0.y + bb.y);
        v1.x = K2LE * (a1.x + bb.x); v1.y = K2LE * (a1.y + bb.y);
        *(float2*)&H[(size_t)(m0 + r0) * 128 + lane * 2]     = v0;
        *(float2*)&H[(size_t)(m0 + r0 + 1) * 128 + lane * 2] = v1;
    }
}

// ---- attention: tanh ctx + softmax + dset -> x; 4 rows/block, grid 512 ----
__global__ __launch_bounds__(512) void attn_kernel(
    const float* __restrict__ obs, const float* __restrict__ Wc,
    const float* __restrict__ Wa,  const float* __restrict__ ba,
    float* __restrict__ ws)
{
    __shared__ float s_obs[4][512];    // 8 KB
    __shared__ float s_ht[4][128];     // 2 KB (K2LE-prescaled)
    __shared__ float s_alog[4][512];   // 8 KB
    __shared__ float s_wc0[128], s_wa2[128];

    const int tid = threadIdx.x;
    const int row0 = blockIdx.x * 4;
    const float* hterm = ws + HTERM_OFF;
    float* X = ws + X_OFF;

    {   // one float4 per thread
        int r = tid >> 7, kq = tid & 127;
        *(float4*)&s_obs[r][kq * 4] =
            *(const float4*)&obs[(size_t)(row0 + r) * 512 + kq * 4];
    }
    if (tid < 128) {            // hterm: 4 rows x 32 quads
        int r = tid >> 5, kq = tid & 31;
        *(float4*)&s_ht[r][kq * 4] =
            *(const float4*)&hterm[(size_t)(row0 + r) * 128 + kq * 4];
    } else if (tid < 256) {
        int t = tid - 128;
        s_wc0[t] = K2LE * Wc[t * (HM + 1)];
        s_wa2[t] = 2.0f * Wa[t];
    }
    __syncthreads();

    {
        const float ba0 = ba[0];
        const int o = tid;
        float ob[4], acA[4];
        #pragma unroll
        for (int r = 0; r < 4; ++r) { ob[r] = s_obs[r][o]; acA[r] = 0.f; }
        float swa = 0.f;
        for (int c = 0; c < 128; c += 4) {
            float4 v = *(const float4*)&s_wa2[c];
            swa += v.x + v.y + v.z + v.w;
        }
        swa *= 0.5f;
        for (int c4 = 0; c4 < 32; ++c4) {
            float4 wc = *(const float4*)&s_wc0[c4 * 4];
            float4 wa = *(const float4*)&s_wa2[c4 * 4];
            #pragma unroll
            for (int r = 0; r < 4; ++r) {
                float4 ht = *(const float4*)&s_ht[r][c4 * 4];
                float t0 = fmaf(ob[r], wc.x, ht.x);
                acA[r] = fmaf(wa.x, RCPF(EXP2F(t0) + 1.f), acA[r]);
                float t1 = fmaf(ob[r], wc.y, ht.y);
                acA[r] = fmaf(wa.y, RCPF(EXP2F(t1) + 1.f), acA[r]);
                float t2 = fmaf(ob[r], wc.z, ht.z);
                acA[r] = fmaf(wa.z, RCPF(EXP2F(t2) + 1.f), acA[r]);
                float t3 = fmaf(ob[r], wc.w, ht.w);
                acA[r] = fmaf(wa.w, RCPF(EXP2F(t3) + 1.f), acA[r]);
            }
        }
        #pragma unroll
        for (int r = 0; r < 4; ++r) s_alog[r][o] = ba0 + swa - acA[r];
    }
    __syncthreads();

    {
        const int wv = tid >> 6, lane = tid & 63;
        if (wv < 4) {
            const int r = wv;
            float m = -1e30f;
            for (int o = lane; o < 512; o += 64) m = fmaxf(m, s_alog[r][o]);
            #pragma unroll
            for (int d = 32; d >= 1; d >>= 1) m = fmaxf(m, __shfl_xor(m, d));
            float se = 0.f, sw = 0.f;
            for (int o = lane; o < 512; o += 64) {
                float e = __expf(s_alog[r][o] - m);
                se += e; sw += e * s_obs[r][o];
            }
            #pragma unroll
            for (int d = 32; d >= 1; d >>= 1) { se += __shfl_xor(se, d); sw += __shfl_xor(sw, d); }
            if (lane == 0) X[row0 + r] = sw / se;
        }
    }
}

// ---- fused: GRU-finish + out2 GEMM (2-way cross-wave k-split) + heads ----
__global__ __launch_bounds__(512) void out2_heads(
    const float* __restrict__ hmem,  const float* __restrict__ W_ih,
    const float* __restrict__ b_ih,  const float* __restrict__ b2,
    const float* __restrict__ Wact,  const float* __restrict__ bact,
    const float* __restrict__ Wcrit, const float* __restrict__ bcrit,
    const float* __restrict__ ws,    float* __restrict__ out)
{
    __shared__ float s_act[8 * 768];   // 24 KB; aliased as s_out[8][512] after GEMM
    __shared__ float s_P[8 * 512];     // 16 KB partials (kg=1)
    const int tid = threadIdx.x;
    const int wv = tid >> 6, lane = tid & 63;
    const int m0 = blockIdx.x * 8;
    const float* F = ws + FEAT_OFF;
    const float* G = ws + GATES_OFF;
    const float* X = ws + X_OFF;

    // stage feat rows into [r][0..512)
    for (int i = tid; i < 1024; i += 512) {
        int r = i >> 7, kq = i & 127;
        *(float4*)&s_act[r * 768 + kq * 4] =
            *(const float4*)&F[(size_t)(m0 + r) * 512 + kq * 4];
    }
    // GRU finish -> [r][512..768)
    for (int i = tid; i < 2048; i += 512) {
        int r = i >> 8, j = i & 255;
        int grow = m0 + r;
        float g0 = G[(size_t)grow * 768 + j];
        float g1 = G[(size_t)grow * 768 + 256 + j];
        float g2 = G[(size_t)grow * 768 + 512 + j];
        float hp = hmem[(size_t)grow * 256 + j];
        float x  = X[grow];
        float rg = fast_sig(fmaf(x, W_ih[j], b_ih[j]) + g0);
        float zg = fast_sig(fmaf(x, W_ih[256 + j], b_ih[256 + j]) + g1);
        float ng = fast_tanh(fmaf(x, W_ih[512 + j], b_ih[512 + j]) + rg * g2);
        s_act[r * 768 + 512 + j] = (1.0f - zg) * ng + zg * hp;
    }
    __syncthreads();

    // out2 GEMM: 8 waves = (kg = wv&1) x (colgroup = wv>>1); lanes own f2 col-pairs
    const float2* __restrict__ Wt = (const float2*)(ws + W2T_OFF);  // [768][256 f2]
    const int kg = wv & 1, cg = wv >> 1;
    const int c2 = cg * 64 + lane;
    const int k0 = kg * 384;
    float2 acc[8];
    #pragma unroll
    for (int r = 0; r < 8; ++r) acc[r] = make_float2(0.f, 0.f);
    #pragma unroll 4
    for (int k = k0; k < k0 + 384; k += 4) {
        float2 w0 = Wt[(k + 0) * 256 + c2];
        float2 w1 = Wt[(k + 1) * 256 + c2];
        float2 w2 = Wt[(k + 2) * 256 + c2];
        float2 w3 = Wt[(k + 3) * 256 + c2];
        #pragma unroll
        for (int r = 0; r < 8; ++r) {
            float4 o = *(const float4*)&s_act[r * 768 + k];  // uniform broadcast
            acc[r].x = fmaf(o.x, w0.x, acc[r].x); acc[r].y = fmaf(o.x, w0.y, acc[r].y);
            acc[r].x = fmaf(o.y, w1.x, acc[r].x); acc[r].y = fmaf(o.y, w1.y, acc[r].y);
            acc[r].x = fmaf(o.z, w2.x, acc[r].x); acc[r].y = fmaf(o.z, w2.y, acc[r].y);
            acc[r].x = fmaf(o.w, w3.x, acc[r].x); acc[r].y = fmaf(o.w, w3.y, acc[r].y);
        }
    }
    float2* P2 = (float2*)s_P;
    if (kg == 1) {
        #pragma unroll
        for (int r = 0; r < 8; ++r) P2[r * 256 + c2] = acc[r];
    }
    __syncthreads();            // partials ready; all s_act reads done
    float (*s_out)[512] = (float (*)[512])s_act;
    if (kg == 0) {
        float2 bb = ((const float2*)b2)[c2];
        #pragma unroll
        for (int r = 0; r < 8; ++r) {
            float2 p = P2[r * 256 + c2];
            float2 v;
            v.x = fmaxf(acc[r].x + p.x + bb.x, 0.f);
            v.y = fmaxf(acc[r].y + p.y + bb.y, 0.f);
            *(float2*)&s_out[r][c2 * 2] = v;
        }
    }
    __syncthreads();

    // heads: 8 waves, wave wv owns row wv
    {
        const int rr = wv;
        const int grow = m0 + rr;
        float4 x0 = *(const float4*)&s_out[rr][lane * 8];
        float4 x1 = *(const float4*)&s_out[rr][lane * 8 + 4];
        float la[ACT];
        #pragma unroll
        for (int a = 0; a < ACT; ++a) {
            const float4* wa4 = (const float4*)&Wact[a * HS2 + lane * 8];
            float4 w0 = wa4[0], w1 = wa4[1];
            float p = x0.x * w0.x + x0.y * w0.y + x0.z * w0.z + x0.w * w0.w
                    + x1.x * w1.x + x1.y * w1.y + x1.z * w1.z + x1.w * w1.w;
            #pragma unroll
            for (int d = 32; d >= 1; d >>= 1) p += __shfl_xor(p, d);
            la[a] = p + bact[a];
        }
        const float4* wc4 = (const float4*)&Wcrit[lane * 8];
        float4 w0 = wc4[0], w1 = wc4[1];
        float pv = x0.x * w0.x + x0.y * w0.y + x0.z * w0.z + x0.w * w0.w
                 + x1.x * w1.x + x1.y * w1.y + x1.z * w1.z + x1.w * w1.w;
        #pragma unroll
        for (int d = 32; d >= 1; d >>= 1) pv += __shfl_xor(pv, d);

        float g = (lane < ACT) ? gumbel_ra(grow, lane) : 0.0f;
        float best = -1e30f; int amax = 0;
        float mx = -1e30f;
        #pragma unroll
        for (int a = 0; a < ACT; ++a) {
            float g_ = __shfl(g, a);
            float y = la[a] + g_;
            if (y > best) { best = y; amax = a; }   // first-max tie-break
            mx = fmaxf(mx, la[a]);
        }
        float se = 0.f;
        #pragma unroll
        for (int a = 0; a < ACT; ++a) se += __expf(la[a] - mx);
        float lse = mx + logf(se);
        float lp = la[amax] - lse;
        if (lane == 0) {
            out[grow]          = (float)amax;
            out[NW + grow]     = pv + bcrit[0];
            out[2 * NW + grow] = lp;
        }
    }
}

extern "C" void kernel_launch(void* const* d_in, const int* in_sizes, int n_in,
                              void* d_out, int out_size, void* d_ws, size_t ws_size,
                              hipStream_t stream) {
    const float* obs   = (const float*)d_in[0];
    const float* hmem  = (const float*)d_in[1];
    const float* W1    = (const float*)d_in[2];
    const float* b1    = (const float*)d_in[3];
    const float* Wc    = (const float*)d_in[4];
    const float* bc    = (const float*)d_in[5];
    const float* Wa    = (const float*)d_in[6];
    const float* ba    = (const float*)d_in[7];
    const float* W_ih  = (const float*)d_in[8];
    const float* b_ih  = (const float*)d_in[9];
    const float* W_hh  = (const float*)d_in[10];
    const float* b_hh  = (const float*)d_in[11];
    const float* W2    = (const float*)d_in[12];
    const float* b2    = (const float*)d_in[13];
    const float* Wact  = (const float*)d_in[14];
    const float* bact  = (const float*)d_in[15];
    const float* Wcrit = (const float*)d_in[16];
    const float* bcrit = (const float*)d_in[17];
    float* ws = (float*)d_ws;

    transpose_weights<<<736, 256, 0, stream>>>(W1, Wc, W_hh, W2, ws);
    gemm8<<<768, 256, 0, stream>>>(obs, hmem, b1, bc, b_hh, ws);
    attn_kernel<<<512, 512, 0, stream>>>(obs, Wc, Wa, ba, ws);
    out2_heads<<<256, 512, 0, stream>>>(hmem, W_ih, b_ih, b2,
                                        Wact, bact, Wcrit, bcrit, ws, (float*)d_out);
}

// Round 11
// 119.169 us; speedup vs baseline: 1.1536x; 1.0554x over previous
//
#include <hip/hip_runtime.h>
#include <stdint.h>

#define NW   2048
#define OBS  512
#define HS   512
#define HS2  512
#define HM   256
#define CTX  128
#define ACT  18

#define K2LE 2.8853900817779268f   // 2*log2(e)

// ws layout (floats)
#define W1T_OFF   0          // [512 k][512 c]
#define WCT_OFF   262144     // [256 m][128 c]
#define W2T_OFF   294912     // [768 k][512 c]
#define WHHQ_OFF  688128     // [256 m][256 j] float4 (Wr,Wz,Wn,0)
#define FEAT_OFF  950272     // [2048][512]
#define GATES_OFF 1998848    // [2048][768]  (b_hh added)
#define HTERM_OFF 3571712    // [2048][128]  (K2LE-prescaled, bc added)
#define X_OFF     3833856    // [2048]
#define OUT2_OFF  3835904    // [2048][512]
// total 4,884,480 floats = 19.5 MB

#if __has_builtin(__builtin_amdgcn_exp2f)
#define EXP2F(x) __builtin_amdgcn_exp2f(x)
#else
#define EXP2F(x) exp2f(x)
#endif
#if __has_builtin(__builtin_amdgcn_rcpf)
#define RCPF(x) __builtin_amdgcn_rcpf(x)
#else
#define RCPF(x) (1.0f/(x))
#endif

// ---------------- threefry2x32 (key = (0,42)), 20 rounds ----------------
#define TFR(x0, x1, R) { x0 += x1; x1 = (x1 << R) | (x1 >> (32 - R)); x1 ^= x0; }

__device__ __forceinline__ void threefry_0_42(uint32_t x0, uint32_t x1,
                                              uint32_t& o0, uint32_t& o1) {
    const uint32_t ks0 = 0u;
    const uint32_t ks1 = 42u;
    const uint32_t ks2 = 0x1BD11BDAu ^ ks0 ^ ks1;
    x0 += ks0; x1 += ks1;
    TFR(x0, x1, 13) TFR(x0, x1, 15) TFR(x0, x1, 26) TFR(x0, x1, 6)
    x0 += ks1; x1 += ks2 + 1u;
    TFR(x0, x1, 17) TFR(x0, x1, 29) TFR(x0, x1, 16) TFR(x0, x1, 24)
    x0 += ks2; x1 += ks0 + 2u;
    TFR(x0, x1, 13) TFR(x0, x1, 15) TFR(x0, x1, 26) TFR(x0, x1, 6)
    x0 += ks0; x1 += ks1 + 3u;
    TFR(x0, x1, 17) TFR(x0, x1, 29) TFR(x0, x1, 16) TFR(x0, x1, 24)
    x0 += ks1; x1 += ks2 + 4u;
    TFR(x0, x1, 13) TFR(x0, x1, 15) TFR(x0, x1, 26) TFR(x0, x1, 6)
    x0 += ks2; x1 += ks0 + 5u;
    o0 = x0; o1 = x1;
}

// jax_threefry_partitionable scheme (verified round 2): counter=(0,n), out0^out1
__device__ __forceinline__ float gumbel_ra(int row, int a) {
    uint32_t n = (uint32_t)(row * ACT + a);
    uint32_t o0, o1;
    threefry_0_42(0u, n, o0, o1);
    uint32_t bits = o0 ^ o1;
    uint32_t fb = (bits >> 9) | 0x3F800000u;
    float f = __uint_as_float(fb) - 1.0f;
    const float tiny = 1.17549435e-38f;
    float u = (f < tiny) ? tiny : f;
    return -logf(-logf(u));
}

__device__ __forceinline__ float fast_tanh(float x) {
    float e = __expf(2.0f * x);
    return 1.0f - 2.0f / (e + 1.0f);
}
__device__ __forceinline__ float fast_sig(float x) {
    return 1.0f / (1.0f + __expf(-x));
}

// ---- weight prep: transposes + GRU gate-pack into ws ----
__global__ __launch_bounds__(256) void transpose_weights(
    const float* __restrict__ W1, const float* __restrict__ Wc,
    const float* __restrict__ Whh, const float* __restrict__ W2,
    float* __restrict__ ws)
{
    __shared__ float t[3][32][33];
    const int tx = threadIdx.x & 31, ty = threadIdx.x >> 5;   // 32 x 8
    int b = blockIdx.x;
    if (b < 672) {
        const float* src; float* dst; int ld, off, R, it, jt;
        if (b < 256)      { src = W1;  dst = ws + W1T_OFF;  ld = 512; off = 0; it = b >> 4; jt = b & 15; R = 512; }
        else if (b < 288) { int bb = b - 256; src = Wc;  dst = ws + WCT_OFF;  ld = 257; off = 1; it = bb >> 3; jt = bb & 7;  R = 128; }
        else              { int bb = b - 288; src = W2;  dst = ws + W2T_OFF;  ld = 768; off = 0; it = bb / 24; jt = bb % 24; R = 512; }
        const int i0 = it * 32, j0 = jt * 32;
        #pragma unroll
        for (int q = 0; q < 4; ++q)
            t[0][ty + 8 * q][tx] = src[(i0 + ty + 8 * q) * ld + off + j0 + tx];
        __syncthreads();
        #pragma unroll
        for (int q = 0; q < 4; ++q)
            dst[(j0 + ty + 8 * q) * R + i0 + tx] = t[0][tx][ty + 8 * q];
    } else {
        int bb = b - 672;
        const int mt = bb >> 3, jt = bb & 7;
        const int m0 = mt * 32, j0 = jt * 32;
        #pragma unroll
        for (int g = 0; g < 3; ++g)
            #pragma unroll
            for (int q = 0; q < 4; ++q)
                t[g][ty + 8 * q][tx] = Whh[(g * HM + j0 + ty + 8 * q) * HM + m0 + tx];
        __syncthreads();
        float4* dst = (float4*)(ws + WHHQ_OFF);
        #pragma unroll
        for (int q = 0; q < 4; ++q) {
            int ml = ty + 8 * q, jl = tx;
            dst[(size_t)(m0 + ml) * HM + j0 + jl] =
                make_float4(t[0][jl][ml], t[1][jl][ml], t[2][jl][ml], 0.0f);
        }
    }
}

// ---- gemm8: 8 rows/block; wave owns full K; conflict-free broadcasts ----
// grid: [0,256) feat; [256,512) gates; [512,768) hterm
__global__ __launch_bounds__(256) void gemm8(
    const float* __restrict__ obs, const float* __restrict__ hmem,
    const float* __restrict__ b1,  const float* __restrict__ bc,
    const float* __restrict__ bhh, float* __restrict__ ws)
{
    __shared__ float s_act[8 * 512];
    const int tid = threadIdx.x;
    const int wv = tid >> 6, lane = tid & 63;
    const int bid = blockIdx.x;

    if (bid < 256) {
        const int m0 = bid * 8;
        for (int i = tid; i < 1024; i += 256) {
            int r = i >> 7, kq = i & 127;
            *(float4*)&s_act[r * 512 + kq * 4] =
                *(const float4*)&obs[(size_t)(m0 + r) * 512 + kq * 4];
        }
        __syncthreads();
        const float2* __restrict__ Wt = (const float2*)(ws + W1T_OFF);  // [512][256 f2]
        const int c2 = wv * 64 + lane;
        float2 acc[8];
        #pragma unroll
        for (int r = 0; r < 8; ++r) acc[r] = make_float2(0.f, 0.f);
        #pragma unroll 4
        for (int k = 0; k < 512; k += 4) {
            float2 w0 = Wt[(k + 0) * 256 + c2];
            float2 w1 = Wt[(k + 1) * 256 + c2];
            float2 w2 = Wt[(k + 2) * 256 + c2];
            float2 w3 = Wt[(k + 3) * 256 + c2];
            #pragma unroll
            for (int r = 0; r < 8; ++r) {
                float4 o = *(const float4*)&s_act[r * 512 + k];  // uniform broadcast
                acc[r].x = fmaf(o.x, w0.x, acc[r].x); acc[r].y = fmaf(o.x, w0.y, acc[r].y);
                acc[r].x = fmaf(o.y, w1.x, acc[r].x); acc[r].y = fmaf(o.y, w1.y, acc[r].y);
                acc[r].x = fmaf(o.z, w2.x, acc[r].x); acc[r].y = fmaf(o.z, w2.y, acc[r].y);
                acc[r].x = fmaf(o.w, w3.x, acc[r].x); acc[r].y = fmaf(o.w, w3.y, acc[r].y);
            }
        }
        float2 bb = ((const float2*)b1)[c2];
        float* F = ws + FEAT_OFF;
        #pragma unroll
        for (int r = 0; r < 8; ++r) {
            float2 v;
            v.x = fmaxf(acc[r].x + bb.x, 0.f);
            v.y = fmaxf(acc[r].y + bb.y, 0.f);
            *(float2*)&F[(size_t)(m0 + r) * 512 + c2 * 2] = v;
        }
    } else if (bid < 512) {
        const int m0 = (bid - 256) * 8;
        for (int i = tid; i < 512; i += 256) {
            int r = i >> 6, kq = i & 63;
            *(float4*)&s_act[r * 256 + kq * 4] =
                *(const float4*)&hmem[(size_t)(m0 + r) * 256 + kq * 4];
        }
        __syncthreads();
        const float4* __restrict__ Q = (const float4*)(ws + WHHQ_OFF);  // [256][256]
        const int j = wv * 64 + lane;
        float ar[8] = {0,0,0,0,0,0,0,0}, az[8] = {0,0,0,0,0,0,0,0}, an[8] = {0,0,0,0,0,0,0,0};
        #pragma unroll 4
        for (int k = 0; k < 256; k += 4) {
            float4 q0 = Q[(k + 0) * 256 + j];
            float4 q1 = Q[(k + 1) * 256 + j];
            float4 q2 = Q[(k + 2) * 256 + j];
            float4 q3 = Q[(k + 3) * 256 + j];
            #pragma unroll
            for (int r = 0; r < 8; ++r) {
                float4 h = *(const float4*)&s_act[r * 256 + k];  // uniform broadcast
                ar[r] = fmaf(h.x, q0.x, ar[r]); az[r] = fmaf(h.x, q0.y, az[r]); an[r] = fmaf(h.x, q0.z, an[r]);
                ar[r] = fmaf(h.y, q1.x, ar[r]); az[r] = fmaf(h.y, q1.y, az[r]); an[r] = fmaf(h.y, q1.z, an[r]);
                ar[r] = fmaf(h.z, q2.x, ar[r]); az[r] = fmaf(h.z, q2.y, az[r]); an[r] = fmaf(h.z, q2.z, an[r]);
                ar[r] = fmaf(h.w, q3.x, ar[r]); az[r] = fmaf(h.w, q3.y, az[r]); an[r] = fmaf(h.w, q3.z, an[r]);
            }
        }
        float br = bhh[j], bz = bhh[HM + j], bn = bhh[2 * HM + j];
        float* G = ws + GATES_OFF;
        #pragma unroll
        for (int r = 0; r < 8; ++r) {
            size_t base = (size_t)(m0 + r) * 768 + j;
            G[base]       = ar[r] + br;
            G[base + 256] = az[r] + bz;
            G[base + 512] = an[r] + bn;
        }
    } else {
        const int m0 = (bid - 512) * 8;
        for (int i = tid; i < 512; i += 256) {
            int r = i >> 6, kq = i & 63;
            *(float4*)&s_act[r * 256 + kq * 4] =
                *(const float4*)&hmem[(size_t)(m0 + r) * 256 + kq * 4];
        }
        __syncthreads();
        const float2* __restrict__ Wt = (const float2*)(ws + WCT_OFF);  // [256][64 f2]
        const int r0 = wv * 2;
        float2 a0 = make_float2(0.f, 0.f), a1 = make_float2(0.f, 0.f);
        #pragma unroll 4
        for (int k = 0; k < 256; k += 4) {
            float2 w0 = Wt[(k + 0) * 64 + lane];
            float2 w1 = Wt[(k + 1) * 64 + lane];
            float2 w2 = Wt[(k + 2) * 64 + lane];
            float2 w3 = Wt[(k + 3) * 64 + lane];
            float4 o0 = *(const float4*)&s_act[r0 * 256 + k];
            float4 o1 = *(const float4*)&s_act[(r0 + 1) * 256 + k];
            a0.x = fmaf(o0.x, w0.x, a0.x); a0.y = fmaf(o0.x, w0.y, a0.y);
            a0.x = fmaf(o0.y, w1.x, a0.x); a0.y = fmaf(o0.y, w1.y, a0.y);
            a0.x = fmaf(o0.z, w2.x, a0.x); a0.y = fmaf(o0.z, w2.y, a0.y);
            a0.x = fmaf(o0.w, w3.x, a0.x); a0.y = fmaf(o0.w, w3.y, a0.y);
            a1.x = fmaf(o1.x, w0.x, a1.x); a1.y = fmaf(o1.x, w0.y, a1.y);
            a1.x = fmaf(o1.y, w1.x, a1.x); a1.y = fmaf(o1.y, w1.y, a1.y);
            a1.x = fmaf(o1.z, w2.x, a1.x); a1.y = fmaf(o1.z, w2.y, a1.y);
            a1.x = fmaf(o1.w, w3.x, a1.x); a1.y = fmaf(o1.w, w3.y, a1.y);
        }
        float2 bb = ((const float2*)bc)[lane];
        float* H = ws + HTERM_OFF;
        float2 v0, v1;
        v0.x = K2LE * (a0.x + bb.x); v0.y = K2LE * (a0.y + bb.y);
        v1.x = K2LE * (a1.x + bb.x); v1.y = K2LE * (a1.y + bb.y);
        *(float2*)&H[(size_t)(m0 + r0) * 128 + lane * 2]     = v0;
        *(float2*)&H[(size_t)(m0 + r0 + 1) * 128 + lane * 2] = v1;
    }
}

// ---- attention: tanh ctx + softmax + dset -> x; 4 rows/block, grid 512 ----
__global__ __launch_bounds__(512) void attn_kernel(
    const float* __restrict__ obs, const float* __restrict__ Wc,
    const float* __restrict__ Wa,  const float* __restrict__ ba,
    float* __restrict__ ws)
{
    __shared__ float s_obs[4][512];
    __shared__ float s_ht[4][128];
    __shared__ float s_alog[4][512];
    __shared__ float s_wc0[128], s_wa2[128];

    const int tid = threadIdx.x;
    const int row0 = blockIdx.x * 4;
    const float* hterm = ws + HTERM_OFF;
    float* X = ws + X_OFF;

    {
        int r = tid >> 7, kq = tid & 127;
        *(float4*)&s_obs[r][kq * 4] =
            *(const float4*)&obs[(size_t)(row0 + r) * 512 + kq * 4];
    }
    if (tid < 128) {
        int r = tid >> 5, kq = tid & 31;
        *(float4*)&s_ht[r][kq * 4] =
            *(const float4*)&hterm[(size_t)(row0 + r) * 128 + kq * 4];
    } else if (tid < 256) {
        int t = tid - 128;
        s_wc0[t] = K2LE * Wc[t * (HM + 1)];
        s_wa2[t] = 2.0f * Wa[t];
    }
    __syncthreads();

    {
        const float ba0 = ba[0];
        const int o = tid;
        float ob[4], acA[4];
        #pragma unroll
        for (int r = 0; r < 4; ++r) { ob[r] = s_obs[r][o]; acA[r] = 0.f; }
        float swa = 0.f;
        for (int c = 0; c < 128; c += 4) {
            float4 v = *(const float4*)&s_wa2[c];
            swa += v.x + v.y + v.z + v.w;
        }
        swa *= 0.5f;
        for (int c4 = 0; c4 < 32; ++c4) {
            float4 wc = *(const float4*)&s_wc0[c4 * 4];
            float4 wa = *(const float4*)&s_wa2[c4 * 4];
            #pragma unroll
            for (int r = 0; r < 4; ++r) {
                float4 ht = *(const float4*)&s_ht[r][c4 * 4];
                float t0 = fmaf(ob[r], wc.x, ht.x);
                acA[r] = fmaf(wa.x, RCPF(EXP2F(t0) + 1.f), acA[r]);
                float t1 = fmaf(ob[r], wc.y, ht.y);
                acA[r] = fmaf(wa.y, RCPF(EXP2F(t1) + 1.f), acA[r]);
                float t2 = fmaf(ob[r], wc.z, ht.z);
                acA[r] = fmaf(wa.z, RCPF(EXP2F(t2) + 1.f), acA[r]);
                float t3 = fmaf(ob[r], wc.w, ht.w);
                acA[r] = fmaf(wa.w, RCPF(EXP2F(t3) + 1.f), acA[r]);
            }
        }
        #pragma unroll
        for (int r = 0; r < 4; ++r) s_alog[r][o] = ba0 + swa - acA[r];
    }
    __syncthreads();

    {
        const int wv = tid >> 6, lane = tid & 63;
        if (wv < 4) {
            const int r = wv;
            float m = -1e30f;
            for (int o = lane; o < 512; o += 64) m = fmaxf(m, s_alog[r][o]);
            #pragma unroll
            for (int d = 32; d >= 1; d >>= 1) m = fmaxf(m, __shfl_xor(m, d));
            float se = 0.f, sw = 0.f;
            for (int o = lane; o < 512; o += 64) {
                float e = __expf(s_alog[r][o] - m);
                se += e; sw += e * s_obs[r][o];
            }
            #pragma unroll
            for (int d = 32; d >= 1; d >>= 1) { se += __shfl_xor(se, d); sw += __shfl_xor(sw, d); }
            if (lane == 0) X[row0 + r] = sw / se;
        }
    }
}

// ---- out2 GEMM: col-split; 8 rows x 256 cols/block; 4-way cross-wave k-split ----
// grid 512: bid = rowb*2 + colb
__global__ __launch_bounds__(512) void out2_gemm(
    const float* __restrict__ hmem,  const float* __restrict__ W_ih,
    const float* __restrict__ b_ih,  const float* __restrict__ b2,
    const float* __restrict__ ws_c,  float* __restrict__ ws)
{
    __shared__ float s_act[8 * 768];   // 24 KB
    __shared__ float s_P[6144];        // 24 KB: [3][8][128] float2
    const int tid = threadIdx.x;
    const int wv = tid >> 6, lane = tid & 63;
    const int rowb = blockIdx.x >> 1, colb = blockIdx.x & 1;
    const int m0 = rowb * 8;
    const float* F = ws_c + FEAT_OFF;
    const float* G = ws_c + GATES_OFF;
    const float* X = ws_c + X_OFF;

    // stage feat rows into [r][0..512)
    for (int i = tid; i < 1024; i += 512) {
        int r = i >> 7, kq = i & 127;
        *(float4*)&s_act[r * 768 + kq * 4] =
            *(const float4*)&F[(size_t)(m0 + r) * 512 + kq * 4];
    }
    // GRU finish -> [r][512..768)
    for (int i = tid; i < 2048; i += 512) {
        int r = i >> 8, j = i & 255;
        int grow = m0 + r;
        float g0 = G[(size_t)grow * 768 + j];
        float g1 = G[(size_t)grow * 768 + 256 + j];
        float g2 = G[(size_t)grow * 768 + 512 + j];
        float hp = hmem[(size_t)grow * 256 + j];
        float x  = X[grow];
        float rg = fast_sig(fmaf(x, W_ih[j], b_ih[j]) + g0);
        float zg = fast_sig(fmaf(x, W_ih[256 + j], b_ih[256 + j]) + g1);
        float ng = fast_tanh(fmaf(x, W_ih[512 + j], b_ih[512 + j]) + rg * g2);
        s_act[r * 768 + 512 + j] = (1.0f - zg) * ng + zg * hp;
    }
    __syncthreads();

    // 8 waves = (kg = wv&3: 192-k slice) x (cg = wv>>2: 64-f2 col group)
    const float2* __restrict__ Wt = (const float2*)(ws_c + W2T_OFF);  // [768][256 f2]
    const int kg = wv & 3, cg = wv >> 2;
    const int c2 = colb * 128 + cg * 64 + lane;   // global f2 col in [0,256)
    const int k0 = kg * 192;
    float2 acc[8];
    #pragma unroll
    for (int r = 0; r < 8; ++r) acc[r] = make_float2(0.f, 0.f);
    #pragma unroll 4
    for (int k = k0; k < k0 + 192; k += 4) {
        float2 w0 = Wt[(k + 0) * 256 + c2];
        float2 w1 = Wt[(k + 1) * 256 + c2];
        float2 w2 = Wt[(k + 2) * 256 + c2];
        float2 w3 = Wt[(k + 3) * 256 + c2];
        #pragma unroll
        for (int r = 0; r < 8; ++r) {
            float4 o = *(const float4*)&s_act[r * 768 + k];  // uniform broadcast
            acc[r].x = fmaf(o.x, w0.x, acc[r].x); acc[r].y = fmaf(o.x, w0.y, acc[r].y);
            acc[r].x = fmaf(o.y, w1.x, acc[r].x); acc[r].y = fmaf(o.y, w1.y, acc[r].y);
            acc[r].x = fmaf(o.z, w2.x, acc[r].x); acc[r].y = fmaf(o.z, w2.y, acc[r].y);
            acc[r].x = fmaf(o.w, w3.x, acc[r].x); acc[r].y = fmaf(o.w, w3.y, acc[r].y);
        }
    }
    float2* P2 = (float2*)s_P;          // [kg-1][r][cg*64+lane]
    const int cl = cg * 64 + lane;      // local f2 col in [0,128)
    if (kg != 0) {
        #pragma unroll
        for (int r = 0; r < 8; ++r) P2[((kg - 1) * 8 + r) * 128 + cl] = acc[r];
    }
    __syncthreads();
    if (kg == 0) {
        float2 bb = ((const float2*)b2)[c2];
        float* O = ws + OUT2_OFF;
        #pragma unroll
        for (int r = 0; r < 8; ++r) {
            float2 p0 = P2[(0 * 8 + r) * 128 + cl];
            float2 p1 = P2[(1 * 8 + r) * 128 + cl];
            float2 p2 = P2[(2 * 8 + r) * 128 + cl];
            float2 v;
            v.x = fmaxf(acc[r].x + p0.x + p1.x + p2.x + bb.x, 0.f);
            v.y = fmaxf(acc[r].y + p0.y + p1.y + p2.y + bb.y, 0.f);
            *(float2*)&ws[OUT2_OFF + (size_t)(m0 + r) * 512 + c2 * 2] = v;
        }
        (void)O;
    }
}

// ---- heads + categorical sampling; wave per row, 8 rows/block ----
__global__ __launch_bounds__(512) void heads_kernel(
    const float* __restrict__ Wact,  const float* __restrict__ bact,
    const float* __restrict__ Wcrit, const float* __restrict__ bcrit,
    const float* __restrict__ ws,    float* __restrict__ out)
{
    const int wv = threadIdx.x >> 6, lane = threadIdx.x & 63;
    const int grow = blockIdx.x * 8 + wv;
    const float* o2 = ws + OUT2_OFF;

    float4 x0 = *(const float4*)&o2[(size_t)grow * 512 + lane * 8];
    float4 x1 = *(const float4*)&o2[(size_t)grow * 512 + lane * 8 + 4];

    float la[ACT];
    #pragma unroll
    for (int a = 0; a < ACT; ++a) {
        const float4* wa4 = (const float4*)&Wact[a * HS2 + lane * 8];
        float4 w0 = wa4[0], w1 = wa4[1];
        float p = x0.x * w0.x + x0.y * w0.y + x0.z * w0.z + x0.w * w0.w
                + x1.x * w1.x + x1.y * w1.y + x1.z * w1.z + x1.w * w1.w;
        #pragma unroll
        for (int d = 32; d >= 1; d >>= 1) p += __shfl_xor(p, d);
        la[a] = p + bact[a];
    }
    const float4* wc4 = (const float4*)&Wcrit[lane * 8];
    float4 w0 = wc4[0], w1 = wc4[1];
    float pv = x0.x * w0.x + x0.y * w0.y + x0.z * w0.z + x0.w * w0.w
             + x1.x * w1.x + x1.y * w1.y + x1.z * w1.z + x1.w * w1.w;
    #pragma unroll
    for (int d = 32; d >= 1; d >>= 1) pv += __shfl_xor(pv, d);

    float g = (lane < ACT) ? gumbel_ra(grow, lane) : 0.0f;
    float best = -1e30f; int amax = 0;
    float mx = -1e30f;
    #pragma unroll
    for (int a = 0; a < ACT; ++a) {
        float g_ = __shfl(g, a);
        float y = la[a] + g_;
        if (y > best) { best = y; amax = a; }   // first-max tie-break
        mx = fmaxf(mx, la[a]);
    }
    float se = 0.f;
    #pragma unroll
    for (int a = 0; a < ACT; ++a) se += __expf(la[a] - mx);
    float lse = mx + logf(se);
    float lp = la[amax] - lse;
    if (lane == 0) {
        out[grow]          = (float)amax;
        out[NW + grow]     = pv + bcrit[0];
        out[2 * NW + grow] = lp;
    }
}

extern "C" void kernel_launch(void* const* d_in, const int* in_sizes, int n_in,
                              void* d_out, int out_size, void* d_ws, size_t ws_size,
                              hipStream_t stream) {
    const float* obs   = (const float*)d_in[0];
    const float* hmem  = (const float*)d_in[1];
    const float* W1    = (const float*)d_in[2];
    const float* b1    = (const float*)d_in[3];
    const float* Wc    = (const float*)d_in[4];
    const float* bc    = (const float*)d_in[5];
    const float* Wa    = (const float*)d_in[6];
    const float* ba    = (const float*)d_in[7];
    const float* W_ih  = (const float*)d_in[8];
    const float* b_ih  = (const float*)d_in[9];
    const float* W_hh  = (const float*)d_in[10];
    const float* b_hh  = (const float*)d_in[11];
    const float* W2    = (const float*)d_in[12];
    const float* b2    = (const float*)d_in[13];
    const float* Wact  = (const float*)d_in[14];
    const float* bact  = (const float*)d_in[15];
    const float* Wcrit = (const float*)d_in[16];
    const float* bcrit = (const float*)d_in[17];
    float* ws = (float*)d_ws;

    transpose_weights<<<736, 256, 0, stream>>>(W1, Wc, W_hh, W2, ws);
    gemm8<<<768, 256, 0, stream>>>(obs, hmem, b1, bc, b_hh, ws);
    attn_kernel<<<512, 512, 0, stream>>>(obs, Wc, Wa, ba, ws);
    out2_gemm<<<512, 512, 0, stream>>>(hmem, W_ih, b_ih, b2, ws, ws);
    heads_kernel<<<256, 512, 0, stream>>>(Wact, bact, Wcrit, bcrit, ws, (float*)d_out);
}